// Round 6
// baseline (236.089 us; speedup 1.0000x reference)
//
#include <hip/hip_runtime.h>

#define T_TOK 16384
#define HDIM  4096
#define NEXP  64
#define TAU   2e-4f
#define BM    128

typedef unsigned short u16;
typedef u16   u16x8  __attribute__((ext_vector_type(8)));
typedef __bf16 bf16x8 __attribute__((ext_vector_type(8)));
typedef float f32x4  __attribute__((ext_vector_type(4)));

// round-to-nearest-even fp32 -> bf16 (as u16)  [HW-verified rounds 3-5]
__device__ __forceinline__ u16 f2bf(float f) {
    unsigned u = __builtin_bit_cast(unsigned, f);
    unsigned r = u + 0x7FFFu + ((u >> 16) & 1u);
    return (u16)(r >> 16);
}
__device__ __forceinline__ float bf2f(u16 h) {
    unsigned u = ((unsigned)h) << 16;
    return __builtin_bit_cast(float, u);
}

__global__ void zero_counter(int* counter) {
    if (threadIdx.x == 0) counter[0] = 0;
}

// ---------------------------------------------------------------------------
// Pre-pass: split W (fp32 64x4096) into bf16 hi/lo in per-k-chunk MFMA
// fragment order (round-4 verbatim, HW-verified).
// Chunk c (64 k) = 1024 units of 16B: [hi 512 | lo 512]; unit q = U ^ k8,
// U = ks*256 + nt*64 + 16*g + (e&15), k8 = 4*ks+g.
// ---------------------------------------------------------------------------
__global__ __launch_bounds__(256)
void wsplit_kernel(const float* __restrict__ w, u16x8* __restrict__ wfrag) {
    const int id  = blockIdx.x * 256 + threadIdx.x;   // 0..32767
    const int e   = id >> 9;
    const int k8g = id & 511;
    const int k   = k8g * 8;

    const float* wp = w + (size_t)e * HDIM + k;
    const float4 v0 = *(const float4*)wp;
    const float4 v1 = *(const float4*)(wp + 4);
    const float fv[8] = {v0.x, v0.y, v0.z, v0.w, v1.x, v1.y, v1.z, v1.w};
    u16x8 hv, lv;
#pragma unroll
    for (int j = 0; j < 8; ++j) {
        const u16 h = f2bf(fv[j]);
        hv[j] = h;
        lv[j] = f2bf(fv[j] - bf2f(h));
    }
    const int chunk = k >> 6;
    const int k8 = (k >> 3) & 7, ks = k8 >> 2, g = k8 & 3, nt = e >> 4;
    const int U = ks * 256 + nt * 64 + 16 * g + (e & 15);
    const int q = U ^ k8;
    wfrag[(size_t)chunk * 1024 + q]       = hv;
    wfrag[(size_t)chunk * 1024 + 512 + q] = lv;
}

// ---------------------------------------------------------------------------
// MFMA GEMM, bf16-split 3-product. Tile = 128 tokens x 64 experts, BK=64.
// 4 waves; wave wv owns M-subtiles 2wv, 2wv+1. LDS 48 KiB in 16B units:
// [W hi 512 | W lo 512 | X hi 1024 | X lo 1024], unit addr ^ k8 swizzle.
// ---------------------------------------------------------------------------
__global__ __launch_bounds__(256, 3)
void gate_gemm_mfma(const float* __restrict__ x, const u16x8* __restrict__ wfrag,
                    float* __restrict__ partial, int ksplit) {
    const int b      = blockIdx.x;
    const int kslice = b % ksplit;
    const int tblk   = b / ksplit;
    const int kspan  = HDIM / ksplit;
    const int k0     = kslice * kspan;
    const int t0     = tblk * BM;

    __shared__ __align__(16) u16 smem[3072 * 8];   // 48 KiB

    const int tid  = threadIdx.x;
    const int lane = tid & 63;
    const int wv   = tid >> 6;

    f32x4 acc[2][4];
#pragma unroll
    for (int m = 0; m < 2; ++m)
#pragma unroll
        for (int nt = 0; nt < 4; ++nt) acc[m][nt] = (f32x4){0.f, 0.f, 0.f, 0.f};

    for (int kc = k0; kc < k0 + kspan; kc += 64) {
        const int chunkIdx = kc >> 6;
        __syncthreads();

        // ---- stage W: linear copy of 1024 16B units (pre-ordered in global)
        const u16x8* wsrc = wfrag + (size_t)chunkIdx * 1024;
#pragma unroll
        for (int i = 0; i < 4; ++i) {
            const int u = tid + 256 * i;
            *(u16x8*)(smem + (size_t)u * 8) = wsrc[u];
        }

        // ---- stage X: 128 rows x 8 k8-groups; split fp32 -> bf16 hi/lo
#pragma unroll
        for (int i = 0; i < 4; ++i) {
            const int L   = tid + 256 * i;   // 0..1023
            const int row = L >> 3;          // 0..127
            const int k8  = L & 7;
            const float* xp = x + (size_t)(t0 + row) * HDIM + kc + 8 * k8;
            const float4 v0 = *(const float4*)xp;
            const float4 v1 = *(const float4*)(xp + 4);
            const float fv[8] = {v0.x, v0.y, v0.z, v0.w, v1.x, v1.y, v1.z, v1.w};
            u16x8 hv, lv;
#pragma unroll
            for (int j = 0; j < 8; ++j) {
                const u16 h = f2bf(fv[j]);
                hv[j] = h;
                lv[j] = f2bf(fv[j] - bf2f(h));
            }
            const int g = k8 & 3, ks = k8 >> 2, mt = row >> 4;
            const int U = ks * 512 + mt * 64 + 16 * g + (row & 15);
            const int phys = U ^ k8;
            *(u16x8*)(smem + (size_t)(1024 + phys) * 8) = hv;
            *(u16x8*)(smem + (size_t)(2048 + phys) * 8) = lv;
        }
        __syncthreads();

        // ---- MFMA: 2 k-steps x 2 M-subtiles x 4 N-tiles x 3 products
#pragma unroll
        for (int ks = 0; ks < 2; ++ks) {
            const int xo = (ks << 2) + (lane >> 4);   // == this lane's k8
            bf16x8 axh[2], axl[2];
#pragma unroll
            for (int m = 0; m < 2; ++m) {
                const int ux = (ks * 512 + (wv * 2 + m) * 64 + lane) ^ xo;
                axh[m] = __builtin_bit_cast(bf16x8, *(const u16x8*)(smem + (size_t)(1024 + ux) * 8));
                axl[m] = __builtin_bit_cast(bf16x8, *(const u16x8*)(smem + (size_t)(2048 + ux) * 8));
            }
#pragma unroll
            for (int nt = 0; nt < 4; ++nt) {
                const int uw = (ks * 256 + nt * 64 + lane) ^ xo;
                const bf16x8 bh = __builtin_bit_cast(bf16x8, *(const u16x8*)(smem + (size_t)uw * 8));
                const bf16x8 bl = __builtin_bit_cast(bf16x8, *(const u16x8*)(smem + (size_t)(512 + uw) * 8));
#pragma unroll
                for (int m = 0; m < 2; ++m) {
                    acc[m][nt] = __builtin_amdgcn_mfma_f32_16x16x32_bf16(axh[m], bh, acc[m][nt], 0, 0, 0);
                    acc[m][nt] = __builtin_amdgcn_mfma_f32_16x16x32_bf16(axh[m], bl, acc[m][nt], 0, 0, 0);
                    acc[m][nt] = __builtin_amdgcn_mfma_f32_16x16x32_bf16(axl[m], bh, acc[m][nt], 0, 0, 0);
                }
            }
        }
    }

    // epilogue: C row = (lane>>4)*4 + r (token), col = lane&15 (expert in nt)
    float* op = partial + (size_t)kslice * T_TOK * NEXP;
    const int ecol = lane & 15;
#pragma unroll
    for (int m = 0; m < 2; ++m) {
        const int trow = t0 + (wv * 2 + m) * 16 + ((lane >> 4) << 2);
#pragma unroll
        for (int nt = 0; nt < 4; ++nt)
#pragma unroll
            for (int r = 0; r < 4; ++r)
                op[(size_t)(trow + r) * NEXP + nt * 16 + ecol] = acc[m][nt][r];
    }
}

// ---------------------------------------------------------------------------
// Top-k (round-4 verbatim): sum K-split partials, fp32 top-17/token, flag
// gap<TAU tokens into an atomic list for the repair pass.
// Outputs (float32): ew(T,8) | ei(T,8) | ci(T,8) | ia(T,8).
// ---------------------------------------------------------------------------
__global__ __launch_bounds__(256)
void gate_topk_f32(const float* __restrict__ partial, int ksplit,
                   float* __restrict__ out, int* __restrict__ list,
                   int* __restrict__ counter) {
    const int wave = threadIdx.x >> 6;
    const int lane = threadIdx.x & 63;
    const int t = blockIdx.x * 4 + wave;

    float l = 0.f;
    for (int s = 0; s < ksplit; ++s)
        l += partial[(size_t)s * T_TOK * NEXP + (size_t)t * NEXP + lane];

    float v = l;
    const int idx = lane;
    float myval = -3.4e38f;
    int   myidx = 0;
#pragma unroll
    for (int r = 0; r < 17; ++r) {
        float bv = v;
        int   bi = idx;
#pragma unroll
        for (int s = 1; s < 64; s <<= 1) {
            const float ov = __shfl_xor(bv, s);
            const int   oi = __shfl_xor(bi, s);
            if (ov > bv || (ov == bv && oi < bi)) { bv = ov; bi = oi; }
        }
        if (lane == r) { myval = bv; myidx = bi; }
        if (idx == bi) v = -3.4e38f;
    }

    const float nxt = __shfl(myval, (lane + 1) & 63);
    const bool close = (lane < 16) && (myval - nxt < TAU);
    if (__ballot(close) != 0ull) {
        if (lane == 0) { const int p = atomicAdd(counter, 1); list[p] = t; }
    }

    const float m = __shfl(myval, 0);
    const float p = (lane < 16) ? expf(myval - m) : 0.f;
    float s8 = (lane < 8) ? p : 0.f;
#pragma unroll
    for (int s = 1; s < 64; s <<= 1) s8 += __shfl_xor(s8, s);

    float* ew = out;
    float* ei = out + (size_t)T_TOK * 8;
    float* ci = out + (size_t)2 * T_TOK * 8;
    float* ia = out + (size_t)3 * T_TOK * 8;
    if (lane < 8) {
        ew[(size_t)t * 8 + lane] = p / s8;
        ei[(size_t)t * 8 + lane] = (float)myidx;
        ia[(size_t)t * 8 + lane] = (float)myidx;
    } else if (lane < 16) {
        ci[(size_t)t * 8 + (lane - 8)] = (float)myidx;
    }
}

// ---------------------------------------------------------------------------
// FP64 repair (round-4 verbatim): wave/token, lane=expert, reads only d_in.
// Idempotent & order-independent -> deterministic despite atomic list order.
// ---------------------------------------------------------------------------
__global__ __launch_bounds__(256)
void gate_repair_f64(const float* __restrict__ x, const float* __restrict__ w,
                     const int* __restrict__ list, const int* __restrict__ counter,
                     float* __restrict__ out) {
    const int lane = threadIdx.x & 63;
    const int wid  = (int)((blockIdx.x * blockDim.x + threadIdx.x) >> 6);
    const int nw   = (int)((gridDim.x * blockDim.x) >> 6);
    const int n    = counter[0];

    for (int i = wid; i < n; i += nw) {
        const int t = __builtin_amdgcn_readfirstlane(list[i]);
        const float* xr = x + (size_t)t * HDIM;
        const float* wr = w + (size_t)lane * HDIM;
        double acc = 0.0;
        for (int k = 0; k < HDIM; k += 4) {
            const float4 xv = *(const float4*)(xr + k);
            const float4 wv = *(const float4*)(wr + k);
            acc = fma((double)xv.x, (double)wv.x, acc);
            acc = fma((double)xv.y, (double)wv.y, acc);
            acc = fma((double)xv.z, (double)wv.z, acc);
            acc = fma((double)xv.w, (double)wv.w, acc);
        }

        double v = acc;
        const int idx = lane;
        double mylog = -1.0e308;
        int    myidx = 0;
#pragma unroll
        for (int r = 0; r < 16; ++r) {
            double bv = v;
            int    bi = idx;
#pragma unroll
            for (int s = 1; s < 64; s <<= 1) {
                const double ov = __shfl_xor(bv, s);
                const int    oi = __shfl_xor(bi, s);
                if (ov > bv || (ov == bv && oi < bi)) { bv = ov; bi = oi; }
            }
            if (lane == r) { mylog = bv; myidx = bi; }
            if (idx == bi) v = -1.0e308;
        }

        const double m = __shfl(mylog, 0);
        const float p = (lane < 16) ? expf((float)(mylog - m)) : 0.f;
        float s8 = (lane < 8) ? p : 0.f;
#pragma unroll
        for (int s = 1; s < 64; s <<= 1) s8 += __shfl_xor(s8, s);

        float* ew = out;
        float* ei = out + (size_t)T_TOK * 8;
        float* ci = out + (size_t)2 * T_TOK * 8;
        float* ia = out + (size_t)3 * T_TOK * 8;
        if (lane < 8) {
            ew[(size_t)t * 8 + lane] = p / s8;
            ei[(size_t)t * 8 + lane] = (float)myidx;
            ia[(size_t)t * 8 + lane] = (float)myidx;
        } else if (lane < 16) {
            ci[(size_t)t * 8 + (lane - 8)] = (float)myidx;
        }
    }
}

extern "C" void kernel_launch(void* const* d_in, const int* in_sizes, int n_in,
                              void* d_out, int out_size, void* d_ws, size_t ws_size,
                              hipStream_t stream) {
    const float* x = (const float*)d_in[0];
    const float* w = (const float*)d_in[1];
    float* out     = (float*)d_out;

    const size_t slice      = (size_t)T_TOK * NEXP * sizeof(float);  // 4 MiB
    const size_t wfragBytes = (size_t)64 * 1024 * 16;                // 1 MiB
    const size_t extra      = wfragBytes + (size_t)T_TOK * sizeof(int) + 64;

    int ksplit = 1;
    if      (ws_size >= 4 * slice + extra) ksplit = 4;
    else if (ws_size >= 2 * slice + extra) ksplit = 2;

    float* partial = (float*)d_ws;
    u16x8* wfrag   = (u16x8*)((char*)d_ws + (size_t)ksplit * slice);
    int*   list    = (int*)((char*)wfrag + wfragBytes);
    int*   counter = list + T_TOK;

    zero_counter<<<1, 64, 0, stream>>>(counter);
    wsplit_kernel<<<128, 256, 0, stream>>>(w, wfrag);
    gate_gemm_mfma<<<ksplit * (T_TOK / BM), 256, 0, stream>>>(x, wfrag, partial, ksplit);
    gate_topk_f32<<<T_TOK / 4, 256, 0, stream>>>(partial, ksplit, out, list, counter);
    gate_repair_f64<<<256, 256, 0, stream>>>(x, w, list, counter, out);
}

// Round 7
// 188.111 us; speedup vs baseline: 1.2551x; 1.2551x over previous
//
#include <hip/hip_runtime.h>

#define T_TOK 16384
#define HDIM  4096
#define NEXP  64
#define TAU   2e-4f
#define BM    128

typedef unsigned short u16;
typedef u16   u16x8  __attribute__((ext_vector_type(8)));
typedef __bf16 bf16x8 __attribute__((ext_vector_type(8)));
typedef float f32x4  __attribute__((ext_vector_type(4)));

// round-to-nearest-even fp32 -> bf16 (as u16)  [HW-verified rounds 3-6]
__device__ __forceinline__ u16 f2bf(float f) {
    unsigned u = __builtin_bit_cast(unsigned, f);
    unsigned r = u + 0x7FFFu + ((u >> 16) & 1u);
    return (u16)(r >> 16);
}
__device__ __forceinline__ float bf2f(u16 h) {
    unsigned u = ((unsigned)h) << 16;
    return __builtin_bit_cast(float, u);
}

__global__ void zero_counter(int* counter) {
    if (threadIdx.x == 0) counter[0] = 0;
}

// ---------------------------------------------------------------------------
// Pre-pass: (a) split W into bf16 hi/lo in per-k-chunk MFMA fragment order
// (rounds 4/6 verbatim, HW-verified); (b) fp32 transpose wt4[k4][e] for the
// coalesced fp64 repair (each thread writes unique cells -> race-free).
// ---------------------------------------------------------------------------
__global__ __launch_bounds__(256)
void wsplit_kernel(const float* __restrict__ w, u16x8* __restrict__ wfrag,
                   float4* __restrict__ wt4) {
    const int id  = blockIdx.x * 256 + threadIdx.x;   // 0..32767
    const int e   = id >> 9;
    const int k8g = id & 511;
    const int k   = k8g * 8;

    const float* wp = w + (size_t)e * HDIM + k;
    const float4 v0 = *(const float4*)wp;
    const float4 v1 = *(const float4*)(wp + 4);

    // fp32 transpose for repair: wt4[(k/4)*64 + e]
    wt4[(size_t)(2 * k8g) * NEXP + e]     = v0;
    wt4[(size_t)(2 * k8g + 1) * NEXP + e] = v1;

    const float fv[8] = {v0.x, v0.y, v0.z, v0.w, v1.x, v1.y, v1.z, v1.w};
    u16x8 hv, lv;
#pragma unroll
    for (int j = 0; j < 8; ++j) {
        const u16 h = f2bf(fv[j]);
        hv[j] = h;
        lv[j] = f2bf(fv[j] - bf2f(h));
    }
    const int chunk = k >> 6;
    const int k8 = (k >> 3) & 7, ks = k8 >> 2, g = k8 & 3, nt = e >> 4;
    const int U = ks * 256 + nt * 64 + 16 * g + (e & 15);
    const int q = U ^ k8;
    wfrag[(size_t)chunk * 1024 + q]       = hv;
    wfrag[(size_t)chunk * 1024 + 512 + q] = lv;
}

// ---------------------------------------------------------------------------
// MFMA GEMM (round-6 verbatim, replay-stable). Tile = 128x64, BK=64.
// LDS 48 KiB in 16B units: [W hi 512 | W lo 512 | X hi 1024 | X lo 1024],
// unit addr ^ k8 swizzle (bijective, conflict-free).
// ---------------------------------------------------------------------------
__global__ __launch_bounds__(256, 3)
void gate_gemm_mfma(const float* __restrict__ x, const u16x8* __restrict__ wfrag,
                    float* __restrict__ partial, int ksplit) {
    const int b      = blockIdx.x;
    const int kslice = b % ksplit;
    const int tblk   = b / ksplit;
    const int kspan  = HDIM / ksplit;
    const int k0     = kslice * kspan;
    const int t0     = tblk * BM;

    __shared__ __align__(16) u16 smem[3072 * 8];   // 48 KiB

    const int tid  = threadIdx.x;
    const int lane = tid & 63;
    const int wv   = tid >> 6;

    f32x4 acc[2][4];
#pragma unroll
    for (int m = 0; m < 2; ++m)
#pragma unroll
        for (int nt = 0; nt < 4; ++nt) acc[m][nt] = (f32x4){0.f, 0.f, 0.f, 0.f};

    for (int kc = k0; kc < k0 + kspan; kc += 64) {
        const int chunkIdx = kc >> 6;
        __syncthreads();

        // ---- stage W: linear copy of 1024 16B units (pre-ordered in global)
        const u16x8* wsrc = wfrag + (size_t)chunkIdx * 1024;
#pragma unroll
        for (int i = 0; i < 4; ++i) {
            const int u = tid + 256 * i;
            *(u16x8*)(smem + (size_t)u * 8) = wsrc[u];
        }

        // ---- stage X: 128 rows x 8 k8-groups; split fp32 -> bf16 hi/lo
#pragma unroll
        for (int i = 0; i < 4; ++i) {
            const int L   = tid + 256 * i;   // 0..1023
            const int row = L >> 3;          // 0..127
            const int k8  = L & 7;
            const float* xp = x + (size_t)(t0 + row) * HDIM + kc + 8 * k8;
            const float4 v0 = *(const float4*)xp;
            const float4 v1 = *(const float4*)(xp + 4);
            const float fv[8] = {v0.x, v0.y, v0.z, v0.w, v1.x, v1.y, v1.z, v1.w};
            u16x8 hv, lv;
#pragma unroll
            for (int j = 0; j < 8; ++j) {
                const u16 h = f2bf(fv[j]);
                hv[j] = h;
                lv[j] = f2bf(fv[j] - bf2f(h));
            }
            const int g = k8 & 3, ks = k8 >> 2, mt = row >> 4;
            const int U = ks * 512 + mt * 64 + 16 * g + (row & 15);
            const int phys = U ^ k8;
            *(u16x8*)(smem + (size_t)(1024 + phys) * 8) = hv;
            *(u16x8*)(smem + (size_t)(2048 + phys) * 8) = lv;
        }
        __syncthreads();

        // ---- MFMA: 2 k-steps x 2 M-subtiles x 4 N-tiles x 3 products
#pragma unroll
        for (int ks = 0; ks < 2; ++ks) {
            const int xo = (ks << 2) + (lane >> 4);   // == this lane's k8
            bf16x8 axh[2], axl[2];
#pragma unroll
            for (int m = 0; m < 2; ++m) {
                const int ux = (ks * 512 + (wv * 2 + m) * 64 + lane) ^ xo;
                axh[m] = __builtin_bit_cast(bf16x8, *(const u16x8*)(smem + (size_t)(1024 + ux) * 8));
                axl[m] = __builtin_bit_cast(bf16x8, *(const u16x8*)(smem + (size_t)(2048 + ux) * 8));
            }
#pragma unroll
            for (int nt = 0; nt < 4; ++nt) {
                const int uw = (ks * 256 + nt * 64 + lane) ^ xo;
                const bf16x8 bh = __builtin_bit_cast(bf16x8, *(const u16x8*)(smem + (size_t)uw * 8));
                const bf16x8 bl = __builtin_bit_cast(bf16x8, *(const u16x8*)(smem + (size_t)(512 + uw) * 8));
#pragma unroll
                for (int m = 0; m < 2; ++m) {
                    acc[m][nt] = __builtin_amdgcn_mfma_f32_16x16x32_bf16(axh[m], bh, acc[m][nt], 0, 0, 0);
                    acc[m][nt] = __builtin_amdgcn_mfma_f32_16x16x32_bf16(axh[m], bl, acc[m][nt], 0, 0, 0);
                    acc[m][nt] = __builtin_amdgcn_mfma_f32_16x16x32_bf16(axl[m], bh, acc[m][nt], 0, 0, 0);
                }
            }
        }
    }

    // epilogue: C row = (lane>>4)*4 + r (token), col = lane&15 (expert in nt)
    float* op = partial + (size_t)kslice * T_TOK * NEXP;
    const int ecol = lane & 15;
#pragma unroll
    for (int m = 0; m < 2; ++m) {
        const int trow = t0 + (wv * 2 + m) * 16 + ((lane >> 4) << 2);
#pragma unroll
        for (int nt = 0; nt < 4; ++nt)
#pragma unroll
            for (int r = 0; r < 4; ++r)
                op[(size_t)(trow + r) * NEXP + nt * 16 + ecol] = acc[m][nt][r];
    }
}

// ---------------------------------------------------------------------------
// Top-k (round-6 verbatim): sum K-split partials, fp32 top-17/token, flag
// gap<TAU tokens into an atomic list for the repair pass.
// Outputs (float32): ew(T,8) | ei(T,8) | ci(T,8) | ia(T,8).
// ---------------------------------------------------------------------------
__global__ __launch_bounds__(256)
void gate_topk_f32(const float* __restrict__ partial, int ksplit,
                   float* __restrict__ out, int* __restrict__ list,
                   int* __restrict__ counter) {
    const int wave = threadIdx.x >> 6;
    const int lane = threadIdx.x & 63;
    const int t = blockIdx.x * 4 + wave;

    float l = 0.f;
    for (int s = 0; s < ksplit; ++s)
        l += partial[(size_t)s * T_TOK * NEXP + (size_t)t * NEXP + lane];

    float v = l;
    const int idx = lane;
    float myval = -3.4e38f;
    int   myidx = 0;
#pragma unroll
    for (int r = 0; r < 17; ++r) {
        float bv = v;
        int   bi = idx;
#pragma unroll
        for (int s = 1; s < 64; s <<= 1) {
            const float ov = __shfl_xor(bv, s);
            const int   oi = __shfl_xor(bi, s);
            if (ov > bv || (ov == bv && oi < bi)) { bv = ov; bi = oi; }
        }
        if (lane == r) { myval = bv; myidx = bi; }
        if (idx == bi) v = -3.4e38f;
    }

    const float nxt = __shfl(myval, (lane + 1) & 63);
    const bool close = (lane < 16) && (myval - nxt < TAU);
    if (__ballot(close) != 0ull) {
        if (lane == 0) { const int p = atomicAdd(counter, 1); list[p] = t; }
    }

    const float m = __shfl(myval, 0);
    const float p = (lane < 16) ? expf(myval - m) : 0.f;
    float s8 = (lane < 8) ? p : 0.f;
#pragma unroll
    for (int s = 1; s < 64; s <<= 1) s8 += __shfl_xor(s8, s);

    float* ew = out;
    float* ei = out + (size_t)T_TOK * 8;
    float* ci = out + (size_t)2 * T_TOK * 8;
    float* ia = out + (size_t)3 * T_TOK * 8;
    if (lane < 8) {
        ew[(size_t)t * 8 + lane] = p / s8;
        ei[(size_t)t * 8 + lane] = (float)myidx;
        ia[(size_t)t * 8 + lane] = (float)myidx;
    } else if (lane < 16) {
        ci[(size_t)t * 8 + (lane - 8)] = (float)myidx;
    }
}

// ---------------------------------------------------------------------------
// FP64 repair v2: wave/token, lane=expert. W read via wt4 transpose ->
// coalesced 1KB/instr (L2-resident 1 MiB); X read wave-uniform (broadcast).
// 4 independent f64 accumulator chains. Idempotent & order-independent.
// ---------------------------------------------------------------------------
__global__ __launch_bounds__(256)
void gate_repair_f64(const float* __restrict__ x, const float4* __restrict__ wt4,
                     const int* __restrict__ list, const int* __restrict__ counter,
                     float* __restrict__ out) {
    const int lane = threadIdx.x & 63;
    const int wid  = (int)((blockIdx.x * blockDim.x + threadIdx.x) >> 6);
    const int nw   = (int)((gridDim.x * blockDim.x) >> 6);
    const int n    = counter[0];

    for (int i = wid; i < n; i += nw) {
        const int t = __builtin_amdgcn_readfirstlane(list[i]);
        const float4* xr4 = (const float4*)(x + (size_t)t * HDIM);

        double a0 = 0.0, a1 = 0.0, a2 = 0.0, a3 = 0.0;
        for (int k4 = 0; k4 < HDIM / 4; k4 += 4) {
            const float4 w0 = wt4[(size_t)(k4 + 0) * NEXP + lane];
            const float4 w1 = wt4[(size_t)(k4 + 1) * NEXP + lane];
            const float4 w2 = wt4[(size_t)(k4 + 2) * NEXP + lane];
            const float4 w3 = wt4[(size_t)(k4 + 3) * NEXP + lane];
            const float4 x0 = xr4[k4 + 0];
            const float4 x1 = xr4[k4 + 1];
            const float4 x2 = xr4[k4 + 2];
            const float4 x3 = xr4[k4 + 3];
            a0 = fma((double)x0.x, (double)w0.x, a0);
            a0 = fma((double)x0.y, (double)w0.y, a0);
            a0 = fma((double)x0.z, (double)w0.z, a0);
            a0 = fma((double)x0.w, (double)w0.w, a0);
            a1 = fma((double)x1.x, (double)w1.x, a1);
            a1 = fma((double)x1.y, (double)w1.y, a1);
            a1 = fma((double)x1.z, (double)w1.z, a1);
            a1 = fma((double)x1.w, (double)w1.w, a1);
            a2 = fma((double)x2.x, (double)w2.x, a2);
            a2 = fma((double)x2.y, (double)w2.y, a2);
            a2 = fma((double)x2.z, (double)w2.z, a2);
            a2 = fma((double)x2.w, (double)w2.w, a2);
            a3 = fma((double)x3.x, (double)w3.x, a3);
            a3 = fma((double)x3.y, (double)w3.y, a3);
            a3 = fma((double)x3.z, (double)w3.z, a3);
            a3 = fma((double)x3.w, (double)w3.w, a3);
        }
        double v = (a0 + a1) + (a2 + a3);

        const int idx = lane;
        double mylog = -1.0e308;
        int    myidx = 0;
#pragma unroll
        for (int r = 0; r < 16; ++r) {
            double bv = v;
            int    bi = idx;
#pragma unroll
            for (int s = 1; s < 64; s <<= 1) {
                const double ov = __shfl_xor(bv, s);
                const int    oi = __shfl_xor(bi, s);
                if (ov > bv || (ov == bv && oi < bi)) { bv = ov; bi = oi; }
            }
            if (lane == r) { mylog = bv; myidx = bi; }
            if (idx == bi) v = -1.0e308;
        }

        const double m = __shfl(mylog, 0);
        const float p = (lane < 16) ? expf((float)(mylog - m)) : 0.f;
        float s8 = (lane < 8) ? p : 0.f;
#pragma unroll
        for (int s = 1; s < 64; s <<= 1) s8 += __shfl_xor(s8, s);

        float* ew = out;
        float* ei = out + (size_t)T_TOK * 8;
        float* ci = out + (size_t)2 * T_TOK * 8;
        float* ia = out + (size_t)3 * T_TOK * 8;
        if (lane < 8) {
            ew[(size_t)t * 8 + lane] = p / s8;
            ei[(size_t)t * 8 + lane] = (float)myidx;
            ia[(size_t)t * 8 + lane] = (float)myidx;
        } else if (lane < 16) {
            ci[(size_t)t * 8 + (lane - 8)] = (float)myidx;
        }
    }
}

extern "C" void kernel_launch(void* const* d_in, const int* in_sizes, int n_in,
                              void* d_out, int out_size, void* d_ws, size_t ws_size,
                              hipStream_t stream) {
    const float* x = (const float*)d_in[0];
    const float* w = (const float*)d_in[1];
    float* out     = (float*)d_out;

    const size_t slice      = (size_t)T_TOK * NEXP * sizeof(float);   // 4 MiB
    const size_t wfragBytes = (size_t)64 * 1024 * 16;                 // 1 MiB
    const size_t wt4Bytes   = (size_t)NEXP * HDIM * sizeof(float);    // 1 MiB
    const size_t extra      = wfragBytes + wt4Bytes + (size_t)T_TOK * sizeof(int) + 64;

    int ksplit = 1;
    if      (ws_size >= 4 * slice + extra) ksplit = 4;
    else if (ws_size >= 2 * slice + extra) ksplit = 2;

    float*  partial = (float*)d_ws;
    u16x8*  wfrag   = (u16x8*)((char*)d_ws + (size_t)ksplit * slice);
    float4* wt4     = (float4*)((char*)wfrag + wfragBytes);
    int*    list    = (int*)((char*)wt4 + wt4Bytes);
    int*    counter = list + T_TOK;

    zero_counter<<<1, 64, 0, stream>>>(counter);
    wsplit_kernel<<<128, 256, 0, stream>>>(w, wfrag, wt4);
    gate_gemm_mfma<<<ksplit * (T_TOK / BM), 256, 0, stream>>>(x, wfrag, partial, ksplit);
    gate_topk_f32<<<T_TOK / 4, 256, 0, stream>>>(partial, ksplit, out, list, counter);
    gate_repair_f64<<<256, 256, 0, stream>>>(x, wt4, list, counter, out);
}

// Round 8
// 155.216 us; speedup vs baseline: 1.5210x; 1.2119x over previous
//
#include <hip/hip_runtime.h>

#define T_TOK 16384
#define HDIM  4096
#define NEXP  64
#define TAU   2e-4f
#define BM    128

typedef unsigned short u16;
typedef u16   u16x8  __attribute__((ext_vector_type(8)));
typedef __bf16 bf16x8 __attribute__((ext_vector_type(8)));
typedef float f32x4  __attribute__((ext_vector_type(4)));

// round-to-nearest-even fp32 -> bf16 (as u16)  [HW-verified rounds 3-7]
__device__ __forceinline__ u16 f2bf(float f) {
    unsigned u = __builtin_bit_cast(unsigned, f);
    unsigned r = u + 0x7FFFu + ((u >> 16) & 1u);
    return (u16)(r >> 16);
}
__device__ __forceinline__ float bf2f(u16 h) {
    unsigned u = ((unsigned)h) << 16;
    return __builtin_bit_cast(float, u);
}

__global__ void zero_counter(int* counter) {
    if (threadIdx.x == 0) counter[0] = 0;
}

// ---------------------------------------------------------------------------
// Pre-pass (round-7 verbatim): (a) W -> bf16 hi/lo MFMA fragment order;
// (b) fp32 transpose wt4[k4][e] for coalesced f64 repair.
// ---------------------------------------------------------------------------
__global__ __launch_bounds__(256)
void wsplit_kernel(const float* __restrict__ w, u16x8* __restrict__ wfrag,
                   float4* __restrict__ wt4) {
    const int id  = blockIdx.x * 256 + threadIdx.x;   // 0..32767
    const int e   = id >> 9;
    const int k8g = id & 511;
    const int k   = k8g * 8;

    const float* wp = w + (size_t)e * HDIM + k;
    const float4 v0 = *(const float4*)wp;
    const float4 v1 = *(const float4*)(wp + 4);

    wt4[(size_t)(2 * k8g) * NEXP + e]     = v0;
    wt4[(size_t)(2 * k8g + 1) * NEXP + e] = v1;

    const float fv[8] = {v0.x, v0.y, v0.z, v0.w, v1.x, v1.y, v1.z, v1.w};
    u16x8 hv, lv;
#pragma unroll
    for (int j = 0; j < 8; ++j) {
        const u16 h = f2bf(fv[j]);
        hv[j] = h;
        lv[j] = f2bf(fv[j] - bf2f(h));
    }
    const int chunk = k >> 6;
    const int k8 = (k >> 3) & 7, ks = k8 >> 2, g = k8 & 3, nt = e >> 4;
    const int U = ks * 256 + nt * 64 + 16 * g + (e & 15);
    const int q = U ^ k8;
    wfrag[(size_t)chunk * 1024 + q]       = hv;
    wfrag[(size_t)chunk * 1024 + 512 + q] = lv;
}

// ---------------------------------------------------------------------------
// MFMA GEMM (round-6 math/swizzle verbatim) + register prefetch of the next
// K-chunk: globals are issued right after the LDS writes consume the regs,
// so load latency hides under the MFMA phase. LDS 48 KiB, 3 blocks/CU.
// ---------------------------------------------------------------------------
__global__ __launch_bounds__(256, 3)
void gate_gemm_mfma(const float* __restrict__ x, const u16x8* __restrict__ wfrag,
                    float* __restrict__ partial, int ksplit) {
    const int b      = blockIdx.x;
    const int kslice = b % ksplit;
    const int tblk   = b / ksplit;
    const int kspan  = HDIM / ksplit;
    const int k0     = kslice * kspan;
    const int t0     = tblk * BM;

    __shared__ __align__(16) u16 smem[3072 * 8];   // 48 KiB

    const int tid  = threadIdx.x;
    const int lane = tid & 63;
    const int wv   = tid >> 6;

    f32x4 acc[2][4];
#pragma unroll
    for (int m = 0; m < 2; ++m)
#pragma unroll
        for (int nt = 0; nt < 4; ++nt) acc[m][nt] = (f32x4){0.f, 0.f, 0.f, 0.f};

    // prefetch registers (W: 16 VGPR, X: 32 VGPR)
    u16x8  wreg[4];
    float4 xr0[4], xr1[4];

    auto issue = [&](int kc) {
        const u16x8* ws = wfrag + (size_t)(kc >> 6) * 1024;
#pragma unroll
        for (int i = 0; i < 4; ++i) wreg[i] = ws[tid + 256 * i];
#pragma unroll
        for (int i = 0; i < 4; ++i) {
            const int L = tid + 256 * i;
            const int row = L >> 3, k8 = L & 7;
            const float* xp = x + (size_t)(t0 + row) * HDIM + kc + 8 * k8;
            xr0[i] = *(const float4*)xp;
            xr1[i] = *(const float4*)(xp + 4);
        }
    };

    issue(k0);

    for (int kc = k0; kc < k0 + kspan; kc += 64) {
        __syncthreads();   // previous MFMA phase done reading LDS

        // ---- write current chunk from regs to LDS
#pragma unroll
        for (int i = 0; i < 4; ++i)
            *(u16x8*)(smem + (size_t)(tid + 256 * i) * 8) = wreg[i];
#pragma unroll
        for (int i = 0; i < 4; ++i) {
            const int L = tid + 256 * i, row = L >> 3, k8 = L & 7;
            const float fv[8] = {xr0[i].x, xr0[i].y, xr0[i].z, xr0[i].w,
                                 xr1[i].x, xr1[i].y, xr1[i].z, xr1[i].w};
            u16x8 hv, lv;
#pragma unroll
            for (int j = 0; j < 8; ++j) {
                const u16 h = f2bf(fv[j]);
                hv[j] = h;
                lv[j] = f2bf(fv[j] - bf2f(h));
            }
            const int g = k8 & 3, ks = k8 >> 2, mt = row >> 4;
            const int U = ks * 512 + mt * 64 + 16 * g + (row & 15);
            const int phys = U ^ k8;
            *(u16x8*)(smem + (size_t)(1024 + phys) * 8) = hv;
            *(u16x8*)(smem + (size_t)(2048 + phys) * 8) = lv;
        }

        // ---- issue next chunk's globals (in flight during MFMA below)
        if (kc + 64 < k0 + kspan) issue(kc + 64);

        __syncthreads();   // LDS visible

        // ---- MFMA: 2 k-steps x 2 M-subtiles x 4 N-tiles x 3 products
#pragma unroll
        for (int ks = 0; ks < 2; ++ks) {
            const int xo = (ks << 2) + (lane >> 4);   // == this lane's k8
            bf16x8 axh[2], axl[2];
#pragma unroll
            for (int m = 0; m < 2; ++m) {
                const int ux = (ks * 512 + (wv * 2 + m) * 64 + lane) ^ xo;
                axh[m] = __builtin_bit_cast(bf16x8, *(const u16x8*)(smem + (size_t)(1024 + ux) * 8));
                axl[m] = __builtin_bit_cast(bf16x8, *(const u16x8*)(smem + (size_t)(2048 + ux) * 8));
            }
#pragma unroll
            for (int nt = 0; nt < 4; ++nt) {
                const int uw = (ks * 256 + nt * 64 + lane) ^ xo;
                const bf16x8 bh = __builtin_bit_cast(bf16x8, *(const u16x8*)(smem + (size_t)uw * 8));
                const bf16x8 bl = __builtin_bit_cast(bf16x8, *(const u16x8*)(smem + (size_t)(512 + uw) * 8));
#pragma unroll
                for (int m = 0; m < 2; ++m) {
                    acc[m][nt] = __builtin_amdgcn_mfma_f32_16x16x32_bf16(axh[m], bh, acc[m][nt], 0, 0, 0);
                    acc[m][nt] = __builtin_amdgcn_mfma_f32_16x16x32_bf16(axh[m], bl, acc[m][nt], 0, 0, 0);
                    acc[m][nt] = __builtin_amdgcn_mfma_f32_16x16x32_bf16(axl[m], bh, acc[m][nt], 0, 0, 0);
                }
            }
        }
    }

    float* op = partial + (size_t)kslice * T_TOK * NEXP;
    const int ecol = lane & 15;
#pragma unroll
    for (int m = 0; m < 2; ++m) {
        const int trow = t0 + (wv * 2 + m) * 16 + ((lane >> 4) << 2);
#pragma unroll
        for (int nt = 0; nt < 4; ++nt)
#pragma unroll
            for (int r = 0; r < 4; ++r)
                op[(size_t)(trow + r) * NEXP + nt * 16 + ecol] = acc[m][nt][r];
    }
}

// ---------------------------------------------------------------------------
// Top-k (round-6 verbatim): fp32 top-17/token, flag gap<TAU into atomic list.
// ---------------------------------------------------------------------------
__global__ __launch_bounds__(256)
void gate_topk_f32(const float* __restrict__ partial, int ksplit,
                   float* __restrict__ out, int* __restrict__ list,
                   int* __restrict__ counter) {
    const int wave = threadIdx.x >> 6;
    const int lane = threadIdx.x & 63;
    const int t = blockIdx.x * 4 + wave;

    float l = 0.f;
    for (int s = 0; s < ksplit; ++s)
        l += partial[(size_t)s * T_TOK * NEXP + (size_t)t * NEXP + lane];

    float v = l;
    const int idx = lane;
    float myval = -3.4e38f;
    int   myidx = 0;
#pragma unroll
    for (int r = 0; r < 17; ++r) {
        float bv = v;
        int   bi = idx;
#pragma unroll
        for (int s = 1; s < 64; s <<= 1) {
            const float ov = __shfl_xor(bv, s);
            const int   oi = __shfl_xor(bi, s);
            if (ov > bv || (ov == bv && oi < bi)) { bv = ov; bi = oi; }
        }
        if (lane == r) { myval = bv; myidx = bi; }
        if (idx == bi) v = -3.4e38f;
    }

    const float nxt = __shfl(myval, (lane + 1) & 63);
    const bool close = (lane < 16) && (myval - nxt < TAU);
    if (__ballot(close) != 0ull) {
        if (lane == 0) { const int p = atomicAdd(counter, 1); list[p] = t; }
    }

    const float m = __shfl(myval, 0);
    const float p = (lane < 16) ? expf(myval - m) : 0.f;
    float s8 = (lane < 8) ? p : 0.f;
#pragma unroll
    for (int s = 1; s < 64; s <<= 1) s8 += __shfl_xor(s8, s);

    float* ew = out;
    float* ei = out + (size_t)T_TOK * 8;
    float* ci = out + (size_t)2 * T_TOK * 8;
    float* ia = out + (size_t)3 * T_TOK * 8;
    if (lane < 8) {
        ew[(size_t)t * 8 + lane] = p / s8;
        ei[(size_t)t * 8 + lane] = (float)myidx;
        ia[(size_t)t * 8 + lane] = (float)myidx;
    } else if (lane < 16) {
        ci[(size_t)t * 8 + (lane - 8)] = (float)myidx;
    }
}

// ---------------------------------------------------------------------------
// Repair phase 1: one wave per (flagged token, k-slice of 256). Lane=expert,
// coalesced wt4 reads; f64 partial into fpart[li*1024 + ks*64 + e].
// 16x shorter latency chain than the monolithic loop; ~16K waves available.
// ---------------------------------------------------------------------------
__global__ __launch_bounds__(256)
void repair_partial(const float* __restrict__ x, const float4* __restrict__ wt4,
                    const int* __restrict__ list, const int* __restrict__ counter,
                    double* __restrict__ fpart) {
    const int lane = threadIdx.x & 63;
    const int wid  = (int)((blockIdx.x * blockDim.x + threadIdx.x) >> 6);
    const int nw   = (int)((gridDim.x * blockDim.x) >> 6);
    const int nit  = counter[0] * 16;

    for (int it = wid; it < nit; it += nw) {
        const int li = it >> 4;
        const int ks = it & 15;
        const int t  = __builtin_amdgcn_readfirstlane(list[li]);
        const float4* xr4 = (const float4*)(x + (size_t)t * HDIM) + ks * 64;
        const float4* wb  = wt4 + (size_t)ks * 64 * NEXP;

        double a0 = 0.0, a1 = 0.0, a2 = 0.0, a3 = 0.0;
#pragma unroll 4
        for (int j = 0; j < 64; j += 4) {
            const float4 w0 = wb[(size_t)(j + 0) * NEXP + lane];
            const float4 w1 = wb[(size_t)(j + 1) * NEXP + lane];
            const float4 w2 = wb[(size_t)(j + 2) * NEXP + lane];
            const float4 w3 = wb[(size_t)(j + 3) * NEXP + lane];
            const float4 x0 = xr4[j + 0];
            const float4 x1 = xr4[j + 1];
            const float4 x2 = xr4[j + 2];
            const float4 x3 = xr4[j + 3];
            a0 = fma((double)x0.x, (double)w0.x, a0);
            a0 = fma((double)x0.y, (double)w0.y, a0);
            a0 = fma((double)x0.z, (double)w0.z, a0);
            a0 = fma((double)x0.w, (double)w0.w, a0);
            a1 = fma((double)x1.x, (double)w1.x, a1);
            a1 = fma((double)x1.y, (double)w1.y, a1);
            a1 = fma((double)x1.z, (double)w1.z, a1);
            a1 = fma((double)x1.w, (double)w1.w, a1);
            a2 = fma((double)x2.x, (double)w2.x, a2);
            a2 = fma((double)x2.y, (double)w2.y, a2);
            a2 = fma((double)x2.z, (double)w2.z, a2);
            a2 = fma((double)x2.w, (double)w2.w, a2);
            a3 = fma((double)x3.x, (double)w3.x, a3);
            a3 = fma((double)x3.y, (double)w3.y, a3);
            a3 = fma((double)x3.z, (double)w3.z, a3);
            a3 = fma((double)x3.w, (double)w3.w, a3);
        }
        fpart[(size_t)li * 1024 + ks * 64 + lane] = (a0 + a1) + (a2 + a3);
    }
}

// ---------------------------------------------------------------------------
// Repair phase 2: one wave per flagged token. Sum the 16 k-slice partials in
// FIXED order (deterministic regardless of list order), f64 top-16, output.
// ---------------------------------------------------------------------------
__global__ __launch_bounds__(256)
void repair_final(const double* __restrict__ fpart, const int* __restrict__ list,
                  const int* __restrict__ counter, float* __restrict__ out) {
    const int lane = threadIdx.x & 63;
    const int wid  = (int)((blockIdx.x * blockDim.x + threadIdx.x) >> 6);
    const int nw   = (int)((gridDim.x * blockDim.x) >> 6);
    const int n    = counter[0];

    for (int li = wid; li < n; li += nw) {
        const int t = __builtin_amdgcn_readfirstlane(list[li]);

        double v = 0.0;
#pragma unroll
        for (int ks = 0; ks < 16; ++ks)
            v += fpart[(size_t)li * 1024 + ks * 64 + lane];

        const int idx = lane;
        double mylog = -1.0e308;
        int    myidx = 0;
#pragma unroll
        for (int r = 0; r < 16; ++r) {
            double bv = v;
            int    bi = idx;
#pragma unroll
            for (int s = 1; s < 64; s <<= 1) {
                const double ov = __shfl_xor(bv, s);
                const int    oi = __shfl_xor(bi, s);
                if (ov > bv || (ov == bv && oi < bi)) { bv = ov; bi = oi; }
            }
            if (lane == r) { mylog = bv; myidx = bi; }
            if (idx == bi) v = -1.0e308;
        }

        const double m = __shfl(mylog, 0);
        const float p = (lane < 16) ? expf((float)(mylog - m)) : 0.f;
        float s8 = (lane < 8) ? p : 0.f;
#pragma unroll
        for (int s = 1; s < 64; s <<= 1) s8 += __shfl_xor(s8, s);

        float* ew = out;
        float* ei = out + (size_t)T_TOK * 8;
        float* ci = out + (size_t)2 * T_TOK * 8;
        float* ia = out + (size_t)3 * T_TOK * 8;
        if (lane < 8) {
            ew[(size_t)t * 8 + lane] = p / s8;
            ei[(size_t)t * 8 + lane] = (float)myidx;
            ia[(size_t)t * 8 + lane] = (float)myidx;
        } else if (lane < 16) {
            ci[(size_t)t * 8 + (lane - 8)] = (float)myidx;
        }
    }
}

extern "C" void kernel_launch(void* const* d_in, const int* in_sizes, int n_in,
                              void* d_out, int out_size, void* d_ws, size_t ws_size,
                              hipStream_t stream) {
    const float* x = (const float*)d_in[0];
    const float* w = (const float*)d_in[1];
    float* out     = (float*)d_out;

    const size_t slice      = (size_t)T_TOK * NEXP * sizeof(float);     // 4 MiB
    const size_t wfragBytes = (size_t)64 * 1024 * 16;                   // 1 MiB
    const size_t wt4Bytes   = (size_t)NEXP * HDIM * sizeof(float);      // 1 MiB
    const size_t fpartBytes = (size_t)T_TOK * 16 * NEXP * sizeof(double); // 128 MiB
    const size_t extra      = wfragBytes + wt4Bytes + fpartBytes +
                              (size_t)T_TOK * sizeof(int) + 64;

    int ksplit = 1;
    if      (ws_size >= 4 * slice + extra) ksplit = 4;
    else if (ws_size >= 2 * slice + extra) ksplit = 2;

    float*  partial = (float*)d_ws;
    u16x8*  wfrag   = (u16x8*)((char*)d_ws + (size_t)ksplit * slice);
    float4* wt4     = (float4*)((char*)wfrag + wfragBytes);
    double* fpart   = (double*)((char*)wt4 + wt4Bytes);
    int*    list    = (int*)((char*)fpart + fpartBytes);
    int*    counter = list + T_TOK;

    zero_counter<<<1, 64, 0, stream>>>(counter);
    wsplit_kernel<<<128, 256, 0, stream>>>(w, wfrag, wt4);
    gate_gemm_mfma<<<ksplit * (T_TOK / BM), 256, 0, stream>>>(x, wfrag, partial, ksplit);
    gate_topk_f32<<<T_TOK / 4, 256, 0, stream>>>(partial, ksplit, out, list, counter);
    repair_partial<<<4096, 256, 0, stream>>>(x, wt4, list, counter, fpart);
    repair_final<<<1024, 256, 0, stream>>>(fpart, list, counter, out);
}